// Round 10
// baseline (3084.822 us; speedup 1.0000x reference)
//
#include <hip/hip_runtime.h>

// Problem constants (SIZE=68, SSN=8 -> C=9, S1=69, BATCH=256)
#define C9     9
#define S1     69
#define JT     621            // C9*S1: one (class,pos) plane
#define NBATCH 256
#define NSTEP  68
#define QJ     4761           // 69*69   (Q j-stride, P s-major plane size)
#define QI     42849          // 9*69*69 (Q i-stride; also P batch stride)
#define BROW   42849          // 69 planes * 621 per-batch alpha
#define ALPHA_N (NBATCH*BROW)
#define QTFL   385664         // padded float count of one ws region
#define NEGINF (-__builtin_inff())

// float4 with 4-byte alignment guarantee: rows have odd stride 69 floats, so
// 16B alignment is impossible; gfx950 supports dword-aligned dwordx4.
typedef float float4u __attribute__((ext_vector_type(4), aligned(4)));

// Non-temporal load/store: set the `nt` bit -> bypass L1 allocation.  The
// scan's Q stream has ZERO L1 temporal reuse (1.5MB/step >> 32KB L1), and
// the measured per-CU wall (~55GB/s, invariant across r2/r7/r8 structures)
// matches the L1 MSHR-limited rate (outstanding-miss slots x 64B / L2 lat).
// Routing the stream through the deeper L2 queue is the only untried lever
// on that limiter.
__device__ __forceinline__ float4u ntl4(const float* p){
  return __builtin_nontemporal_load((const float4u*)p);
}

// ---------------------------------------------------------------------------
// qtrans: QT[c][t][i][s] = Q[c][i][s][t]  (coalesced backtrace Q reads)
__global__ void qtrans_kernel(const float* __restrict__ Q, float* __restrict__ QT)
{
  __shared__ float tile[69*70];
  const int pl = blockIdx.x;           // c*9 + i
  const int c = pl / 9, i = pl - c*9;
  const float* src = Q + (size_t)pl*QJ;
  for (int f = threadIdx.x; f < QJ; f += 256){
    const int s = f / S1, t = f - s*S1;
    tile[s*70 + t] = src[f];
  }
  __syncthreads();
  float* dst = QT + (size_t)c*QI + i*S1;     // + t*621 + s
  for (int f = threadIdx.x; f < QJ; f += 256){
    const int t = f / S1, s = f - t*S1;
    dst[t*JT + s] = tile[s*70 + t];
  }
}

// ---------------------------------------------------------------------------
// mega v10 = r2's best-known structure (1993us, 704 thr, 4 s-groups x 162
// (j,t-quad) slots, widths {18,17,17,17} exact partition, 2-deep ping-pong,
// 3 barriers/step) with exactly two deltas:
//   1. Q/P scan loads and v-history stores are NON-TEMPORAL (see ntl4).
//   2. the per-step exp-sum shuffle is hoisted out of its divergent guard
//      (r2 shuffled registers of inactive lanes -- worked by luck; sv=0
//      contributions make it sound and bit-identical).
#define SLO(g) ((g)==0 ? 0 : (g)==1 ? 18 : (g)==2 ? 35 : 52)
#define SHI(g) ((g)==0 ? 18 : (g)==1 ? 35 : (g)==2 ? 52 : 69)

#define LOADS(QB, PB, SS) { \
  const float* qs_ = qb + (SS)*S1; \
  _Pragma("unroll") \
  for (int i_ = 0; i_ < C9; ++i_) QB[i_] = ntl4(qs_ + i_*QI); \
  PB = ntl4(pb + (SS)*S1); }

#define COMPS(QB, PB, SS) { \
  float r0=NEGINF, r1=NEGINF, r2=NEGINF, r3=NEGINF; \
  _Pragma("unroll") \
  for (int i_ = 0; i_ < C9; ++i_){ \
    const float lv_ = laC[i_*72 + (SS)]; \
    r0 = fmaxf(r0, fmaf(Tv, QB[i_].x, lv_)); \
    r1 = fmaxf(r1, fmaf(Tv, QB[i_].y, lv_)); \
    r2 = fmaxf(r2, fmaf(Tv, QB[i_].z, lv_)); \
    r3 = fmaxf(r3, fmaf(Tv, QB[i_].w, lv_)); \
  } \
  a0 = fmaxf(a0, PB.x + r0); a1 = fmaxf(a1, PB.y + r1); \
  a2 = fmaxf(a2, PB.z + r2); a3 = fmaxf(a3, PB.w + r3); }

__global__ __launch_bounds__(704) void mega_kernel(
    const float* __restrict__ P, const float* __restrict__ Q,
    const float* __restrict__ pi, const float* __restrict__ Tp,
    const int* __restrict__ ls, float* __restrict__ out,
    const float* __restrict__ QT, int mode)
{
  __shared__ __align__(16) float la[2][C9*72];   // la[buf][i*72 + s]
  __shared__ float part[4][162][4];              // per-group partial maxes
  __shared__ float red[11], sred[11];
  __shared__ float m_sh[NSTEP+1], lse_sh[NSTEP+1], n_sh[NSTEP+1];
  __shared__ float sbest[11];
  __shared__ int   sidx[11];
  __shared__ int   sct[2];

  const int tid  = threadIdx.x;
  const int w    = tid >> 6;
  const int lane = tid & 63;
  const int b    = blockIdx.x;
  const bool act = tid < 648;
  const int gg   = act ? tid / 162 : 3;          // s-group 0..3
  const int slot = act ? tid - (tid/162)*162 : 0;
  const int j    = slot / 18;                    // output class 0..8
  const int tq   = slot - j*18;                  // t-quad 0..17
  const int t0   = (tq < 17) ? 4*tq : 65;        // tq=17 owns only t=68
  const int s_lo = SLO(gg), s_hi = SHI(gg);
  const float Tv = Tp[0];

  float* outb = out + (size_t)b*BROW;

  // ---- prep: v[0] raw (pi at s==0, else -inf); m[0], lse_v[0] ----
  for (int e = tid; e < JT; e += 704){
    const int i = e / S1, s = e - i*S1;
    const float v0 = (s == 0) ? pi[i] : NEGINF;
    outb[68*JT + e] = v0;
    la[0][i*72 + s] = v0;
  }
  if (tid == 0){
    float mx = pi[0];
    #pragma unroll
    for (int c = 1; c < C9; ++c) mx = fmaxf(mx, pi[c]);
    float sm = 0.f;
    #pragma unroll
    for (int c = 0; c < C9; ++c) sm += expf(pi[c] - mx);
    m_sh[0]   = mx;
    lse_sh[0] = mx + logf(sm);
  }
  __syncthreads();
  float mprev = m_sh[0];

  const float* qb = Q + j*QJ + t0;                       // + i*QI + s*S1
  const float* pb = P + (size_t)(b*C9 + j)*QJ + t0;      // + s*S1

  // ---- 68 max-plus steps ----
  int cur = 0;
  for (int k = 1; k <= NSTEP; ++k){
    const float* laC = la[cur];
    float a0 = NEGINF, a1 = NEGINF, a2 = NEGINF, a3 = NEGINF;
    if (act){
      float4u qA[C9], qB[C9], pA, pB;
      int s = s_lo;
      LOADS(qA, pA, s)
      for (; s + 2 < s_hi; s += 2){
        LOADS(qB, pB, s+1)
        COMPS(qA, pA, s)
        LOADS(qA, pA, s+2)
        COMPS(qB, pB, s+1)
      }
      if (s + 1 < s_hi){
        LOADS(qB, pB, s+1)
        COMPS(qA, pA, s)
        COMPS(qB, pB, s+1)
      } else {
        COMPS(qA, pA, s)
      }
      if (gg > 0){
        part[gg][slot][0] = a0; part[gg][slot][1] = a1;
        part[gg][slot][2] = a2; part[gg][slot][3] = a3;
      }
    }
    __syncthreads();                                     // (A) partials ready

    float mval = NEGINF;
    float v0 = 0.f, v1 = 0.f, v2 = 0.f, v3 = 0.f;
    if (act && gg == 0){
      v0 = fmaxf(fmaxf(a0, part[1][slot][0]),
                 fmaxf(part[2][slot][0], part[3][slot][0])) - mprev;
      v1 = fmaxf(fmaxf(a1, part[1][slot][1]),
                 fmaxf(part[2][slot][1], part[3][slot][1])) - mprev;
      v2 = fmaxf(fmaxf(a2, part[1][slot][2]),
                 fmaxf(part[2][slot][2], part[3][slot][2])) - mprev;
      v3 = fmaxf(fmaxf(a3, part[1][slot][3]),
                 fmaxf(part[2][slot][3], part[3][slot][3])) - mprev;
      float* dst = outb + (size_t)(68-k)*JT + j*S1 + t0;
      if (tq < 17){
        float4u vv; vv.x = v0; vv.y = v1; vv.z = v2; vv.w = v3;
        __builtin_nontemporal_store(vv, (float4u*)dst);
        *(float4*)(&la[cur^1][j*72 + t0]) = make_float4(v0, v1, v2, v3);
        mval = fmaxf(fmaxf(v0, v1), fmaxf(v2, v3));
      } else {                                           // owns only t=68
        __builtin_nontemporal_store(v3, dst + 3);
        la[cur^1][j*72 + 68] = v3;
        mval = v3;
      }
    }
    // block max -> m[k]  (only g0 waves 0..2 hold real values)
    float mr = mval;
    #pragma unroll
    for (int o = 32; o >= 1; o >>= 1) mr = fmaxf(mr, __shfl_down(mr, o));
    if (lane == 0) red[w] = mr;
    __syncthreads();                                     // (B)
    float mA = red[0];
    mA = fmaxf(mA, red[1]);
    mA = fmaxf(mA, red[2]);

    // block sum of exp(v - m) -> lse_v[k]
    // (sv computed under the guard, shuffled UNGUARDED: every lane's sv
    // register is defined -- 0 for non-g0 lanes -- so the wave-2 boundary
    // reduce is sound; contributions of 0 keep the math bit-identical.)
    float sv = 0.f;
    if (act && gg == 0){
      if (tq < 17) sv = expf(v0 - mA) + expf(v1 - mA) + expf(v2 - mA) + expf(v3 - mA);
      else         sv = expf(v3 - mA);
    }
    #pragma unroll
    for (int o = 32; o >= 1; o >>= 1) sv += __shfl_down(sv, o);
    if (lane == 0) sred[w] = sv;
    __syncthreads();                                     // (C)
    if (tid == 0){
      const float S = sred[0] + sred[1] + sred[2];
      m_sh[k]   = mA;
      lse_sh[k] = mA + logf(S);
    }
    mprev = mA;
    cur ^= 1;
  }
  __syncthreads();

  // ---- n[k] = lse_v[k] + D[k], D[k] = sum_{kk<k} m[kk] (double) ----
  if (tid == 0){
    double d = 0.0;
    for (int kk = 0; kk <= NSTEP; ++kk){
      n_sh[kk] = (float)((double)lse_sh[kk] + d);
      d += (double)m_sh[kk];
    }
  }
  __syncthreads();

  // ---- addc: alpha[K] = v[68-K] + (n[K] - lse_v[68-K]), clamp -3e38 ----
  for (int K = 0; K <= NSTEP; ++K){
    const float Cst = n_sh[K] - lse_sh[68-K];
    for (int e = tid; e < JT; e += 704){
      float* r = outb + (size_t)K*JT + e;
      *r = fmaxf(*r + Cst, -3.0e38f);
    }
  }
  __syncthreads();

  // ---- backtrace: 621 candidates, one per thread ----
  {
    int c = 3, t2 = ls[b];
    float* mpb = out + (size_t)ALPHA_N + (size_t)b*(69*3);
    if (tid == 0){
      mpb[68*3+0] = 3.f; mpb[68*3+1] = 0.f; mpb[68*3+2] = (float)t2;
      mpb[67*3+1] = 0.f;   // l_0 = 0 after the shift
    }
    const bool vok = tid < JT;
    const int etid = vok ? tid : 0;
    const int im = etid / S1;
    const int sm = etid - im*S1;
    float av = vok ? outb[1*JT + tid] : NEGINF;
    for (int r = 1; r <= NSTEP; ++r){
      float avn = NEGINF;
      if (r < NSTEP && vok) avn = outb[(size_t)(r+1)*JT + tid];
      float best = NEGINF; int bidx = 0x7fffffff;
      if (vok){
        float qv;
        if (mode >= 1) qv = QT[(size_t)(c*S1 + t2)*JT + tid];
        else           qv = Q[c*QI + im*QJ + sm*S1 + t2];
        const float pv = P[(size_t)(b*C9 + c)*QJ + sm*S1 + t2];
        best = (pv + Tv*qv) + av;   // exact ref association
        bidx = tid;
      }
      // argmax: strict > with min-index tie-break == jnp.argmax first-occurrence
      #pragma unroll
      for (int o = 32; o >= 1; o >>= 1){
        const float ov = __shfl_down(best, o); const int oi = __shfl_down(bidx, o);
        if (ov > best || (ov == best && oi < bidx)){ best = ov; bidx = oi; }
      }
      if (lane == 0){ sbest[w] = best; sidx[w] = bidx; }
      __syncthreads();
      if (tid == 0){
        float bb = sbest[0]; int bi = sidx[0];
        #pragma unroll
        for (int q = 1; q < 11; ++q)
          if (sbest[q] > bb || (sbest[q] == bb && sidx[q] < bi)){
            bb = sbest[q]; bi = sidx[q];
          }
        const int cn = bi / S1, tn = bi - cn*S1;
        mpb[(68-r)*3 + 0] = (float)cn;
        mpb[(68-r)*3 + 2] = (float)tn;
        if (r <= 67) mpb[(67-r)*3 + 1] = (float)(tn - t2);
        sct[0] = cn; sct[1] = tn;
      }
      __syncthreads();
      c = sct[0]; t2 = sct[1];
      av = avn;
    }
  }
}

// ---------------------------------------------------------------------------
extern "C" void kernel_launch(void* const* d_in, const int* in_sizes, int n_in,
                              void* d_out, int out_size, void* d_ws, size_t ws_size,
                              hipStream_t stream)
{
  const float* P  = (const float*)d_in[0];
  const float* Q  = (const float*)d_in[1];
  const float* pi = (const float*)d_in[2];
  const float* T  = (const float*)d_in[3];
  const int*   ls = (const int*)d_in[4];

  float* out = (float*)d_out;

  // ws-based transposed Q for coalesced backtrace reads (launch-invariant
  // branch -> graph-safe).
  int mode = 0; float* QT = nullptr;
  if (ws_size >= (size_t)QTFL*4){ mode = 1; QT = (float*)d_ws; }

  if (mode >= 1) qtrans_kernel<<<81, 256, 0, stream>>>(Q, QT);
  mega_kernel<<<NBATCH, 704, 0, stream>>>(P, Q, pi, T, ls, out, QT, mode);
}